// Round 1
// baseline (175.145 us; speedup 1.0000x reference)
//
#include <hip/hip_runtime.h>
#include <hip/hip_bf16.h>
#include <math.h>

// Problem constants (from reference): B=32, L=128, D=512, Qn=16, N=512, P=64
#define DD    512
#define QN    16
#define NTOK  4096           // B*L
#define MEXT  4112           // NTOK + QN (token rows ++ query rows)
#define NGRP  512            // N groups
#define PP    64             // group size
#define SCALE 0.04419417382415922f   // 1/sqrt(512)

// ---------------------------------------------------------------------------
// K1: A[q][e] = sum_d Wk[e][d] * Q0[q][d]   (A = Wk @ Q0^T, stored q-major)
//     c0[q]   = sum_d bk[d] * Q0[q][d]
// grid = 512 + 16 blocks of 1 wave (64 threads)
// ---------------------------------------------------------------------------
__global__ __launch_bounds__(64) void k1_A(
    const float* __restrict__ query, const float* __restrict__ Wk,
    const float* __restrict__ bk, float* __restrict__ A, float* __restrict__ c0)
{
    const int e = blockIdx.x;
    const int lane = threadIdx.x;
    if (e < DD) {
        float x[8];
#pragma unroll
        for (int j = 0; j < 8; ++j) x[j] = Wk[e * DD + j * 64 + lane];
        for (int q = 0; q < QN; ++q) {
            float s = 0.f;
#pragma unroll
            for (int j = 0; j < 8; ++j) s += x[j] * query[q * DD + j * 64 + lane];
#pragma unroll
            for (int off = 32; off > 0; off >>= 1) s += __shfl_down(s, off, 64);
            if (lane == 0) A[q * DD + e] = s;
        }
    } else {
        const int q = e - DD;
        float s = 0.f;
#pragma unroll
        for (int j = 0; j < 8; ++j)
            s += bk[j * 64 + lane] * query[q * DD + j * 64 + lane];
#pragma unroll
        for (int off = 32; off > 0; off >>= 1) s += __shfl_down(s, off, 64);
        if (lane == 0) c0[q] = s;
    }
}

// ---------------------------------------------------------------------------
// K2: Vp_ext = [patch ; Q0] @ Wv + bv      (MEXT x 512 fp32 GEMM, vector ALU)
// 64x64 tile per 256-thread block, 4x4 micro-tile per thread, BK=16
// ---------------------------------------------------------------------------
#define BM 64
#define BN 64
#define BK 16
__global__ __launch_bounds__(256) void k2_gemm(
    const float* __restrict__ patch, const float* __restrict__ query,
    const float* __restrict__ Wv, const float* __restrict__ bv,
    float* __restrict__ C)
{
    __shared__ float Xs[BK][BM + 1];   // [k][m], +1 pad
    __shared__ float Ws[BK][BN];       // [k][n]
    const int tid = threadIdx.x;
    const int rowBase = blockIdx.y * BM;
    const int colBase = blockIdx.x * BN;
    const int tx = tid & 15, ty = tid >> 4;
    const int tx4 = tx * 4, ty4 = ty * 4;
    // loader decomposition
    const int lr = tid >> 2;          // 0..63 : row within X tile
    const int lk = (tid & 3) * 4;     // 0,4,8,12 : k offset (float4)
    const int wr = tid >> 4;          // 0..15 : k within W tile
    const int wc = (tid & 15) * 4;    // col offset (float4)

    float acc[4][4] = {{0.f}};

    for (int k0 = 0; k0 < DD; k0 += BK) {
        // stage X tile (transposed into Xs[k][m])
        const int m = rowBase + lr;
        float4 xv = make_float4(0.f, 0.f, 0.f, 0.f);
        if (m < NTOK)      xv = *(const float4*)&patch[(size_t)m * DD + k0 + lk];
        else if (m < MEXT) xv = *(const float4*)&query[(size_t)(m - NTOK) * DD + k0 + lk];
        Xs[lk + 0][lr] = xv.x; Xs[lk + 1][lr] = xv.y;
        Xs[lk + 2][lr] = xv.z; Xs[lk + 3][lr] = xv.w;
        // stage W tile
        *(float4*)&Ws[wr][wc] = *(const float4*)&Wv[(size_t)(k0 + wr) * DD + colBase + wc];
        __syncthreads();
#pragma unroll
        for (int kk = 0; kk < BK; ++kk) {
            const float a0 = Xs[kk][ty4 + 0];
            const float a1 = Xs[kk][ty4 + 1];
            const float a2 = Xs[kk][ty4 + 2];
            const float a3 = Xs[kk][ty4 + 3];
            const float4 b = *(const float4*)&Ws[kk][tx4];
            acc[0][0] += a0 * b.x; acc[0][1] += a0 * b.y; acc[0][2] += a0 * b.z; acc[0][3] += a0 * b.w;
            acc[1][0] += a1 * b.x; acc[1][1] += a1 * b.y; acc[1][2] += a1 * b.z; acc[1][3] += a1 * b.w;
            acc[2][0] += a2 * b.x; acc[2][1] += a2 * b.y; acc[2][2] += a2 * b.z; acc[2][3] += a2 * b.w;
            acc[3][0] += a3 * b.x; acc[3][1] += a3 * b.y; acc[3][2] += a3 * b.z; acc[3][3] += a3 * b.w;
        }
        __syncthreads();
    }
#pragma unroll
    for (int i = 0; i < 4; ++i) {
        const int m = rowBase + ty4 + i;
        if (m < MEXT) {
#pragma unroll
            for (int j = 0; j < 4; ++j) {
                const int c = colBase + tx4 + j;
                C[(size_t)m * DD + c] = acc[i][j] + bv[c];
            }
        }
    }
}

// ---------------------------------------------------------------------------
// K3: S[t][q] = (X[t,:] . A[q,:] + c0[q]) * scale    for t in [0, MEXT)
//     (rows >= NTOK are the query rows; S[4096+q][q] is s_self[q])
// 1 wave per row, A staged in LDS, conflict-free lane-strided access
// ---------------------------------------------------------------------------
__global__ __launch_bounds__(256) void k3_scores(
    const float* __restrict__ patch, const float* __restrict__ query,
    const float* __restrict__ A, const float* __restrict__ c0,
    float* __restrict__ S)
{
    __shared__ float Als[QN * DD];
    __shared__ float c0s[QN];
    const int tid = threadIdx.x;
    for (int i = tid; i < QN * DD; i += 256) Als[i] = A[i];
    if (tid < QN) c0s[tid] = c0[tid];
    __syncthreads();
    const int wid = tid >> 6, lane = tid & 63;
    const int t = blockIdx.x * 4 + wid;
    if (t >= MEXT) return;
    const float* xrow = (t < NTOK) ? &patch[(size_t)t * DD]
                                   : &query[(size_t)(t - NTOK) * DD];
    float x[8];
#pragma unroll
    for (int j = 0; j < 8; ++j) x[j] = xrow[j * 64 + lane];
    for (int q = 0; q < QN; ++q) {
        float s = 0.f;
#pragma unroll
        for (int j = 0; j < 8; ++j) s += x[j] * Als[q * DD + j * 64 + lane];
#pragma unroll
        for (int off = 32; off > 0; off >>= 1) s += __shfl_down(s, off, 64);
        if (lane == 0) S[t * QN + q] = (s + c0s[q]) * SCALE;
    }
}

// ---------------------------------------------------------------------------
// K4: per-group aggregation. One block (256 thr) per group n.
//   scores -> softmax(65) -> patch_token[q][d] (regs, 2 d/thread)
//   -> fusion softmax over q -> out[n][d]
// ---------------------------------------------------------------------------
__global__ __launch_bounds__(256) void k4_agg(
    const float* __restrict__ Vp,      // MEXT x D (rows >= NTOK are VQ)
    const float* __restrict__ S,       // MEXT x QN
    const int* __restrict__ indices,   // N x P
    const void* __restrict__ pmask,    // N x P, storage width detected
    const float* __restrict__ Wf, const float* __restrict__ bf,
    float* __restrict__ out)
{
    __shared__ int   idxs[PP];
    __shared__ int   mval[PP];
    __shared__ float sc[QN][PP + 2];   // col0 = self, 1..64 = gathered; pad
    __shared__ float red[QN][4];
    __shared__ float fwq[QN];

    const int n = blockIdx.x;
    const int tid = threadIdx.x;

    // --- pos_mask storage-width detection (wave-uniform) ---
    // 4-byte storage (int32 0/1 or fp32 0.0/1.0): nonzero-word test is correct
    // for both. Byte storage (numpy bool): words look like 0x01010101 etc.
    const unsigned int* mw = (const unsigned int*)pmask;
    bool four = true;
#pragma unroll
    for (int i = 0; i < 16; ++i) {
        const unsigned int v = mw[i];
        four = four && (v == 0u || v == 1u || v == 0x3F800000u);
    }

    if (tid < PP) {
        idxs[tid] = indices[n * PP + tid];
        int mv;
        if (four) mv = (mw[n * PP + tid] != 0u);
        else      mv = (((const unsigned char*)pmask)[n * PP + tid] != 0);
        mval[tid] = mv;
    }
    __syncthreads();

    // --- scores ---
    for (int e = tid; e < QN * PP; e += 256) {
        const int q = e & (QN - 1), p = e >> 4;
        sc[q][p + 1] = mval[p] ? S[idxs[p] * QN + q] : -INFINITY;
    }
    if (tid < QN) sc[tid][0] = S[(NTOK + tid) * QN + tid];   // s_self[q]
    __syncthreads();

    // --- softmax over 65 per q (16 lanes, serial 65) ---
    if (tid < QN) {
        const int q = tid;
        float m = -INFINITY;
        for (int j = 0; j <= PP; ++j) m = fmaxf(m, sc[q][j]);
        float s = 0.f;
        for (int j = 0; j <= PP; ++j) { const float e = __expf(sc[q][j] - m); sc[q][j] = e; s += e; }
        const float inv = 1.f / s;
        for (int j = 0; j <= PP; ++j) sc[q][j] *= inv;
    }
    __syncthreads();

    // --- accumulate patch_token: thread owns d0, d0+1 ---
    const int d0 = tid * 2;
    float pt[QN][2];
#pragma unroll
    for (int q = 0; q < QN; ++q) {
        const float w0 = sc[q][0];
        const float2 vq = *(const float2*)&Vp[(size_t)(NTOK + q) * DD + d0];
        pt[q][0] = w0 * vq.x;
        pt[q][1] = w0 * vq.y;
    }
    for (int p = 0; p < PP; ++p) {
        if (!mval[p]) continue;                    // weight is exactly 0
        const float2 v = *(const float2*)&Vp[(size_t)idxs[p] * DD + d0];
#pragma unroll
        for (int q = 0; q < QN; ++q) {
            const float w = sc[q][p + 1];          // LDS broadcast
            pt[q][0] += w * v.x;
            pt[q][1] += w * v.y;
        }
    }

    // --- fusion logits f[q] = patch_token[q,:] . Wf + bf ---
    const float wf0 = Wf[d0], wf1 = Wf[d0 + 1];
    const int wid = tid >> 6, lane = tid & 63;
#pragma unroll
    for (int q = 0; q < QN; ++q) {
        float s = pt[q][0] * wf0 + pt[q][1] * wf1;
#pragma unroll
        for (int off = 32; off > 0; off >>= 1) s += __shfl_down(s, off, 64);
        if (lane == 0) red[q][wid] = s;
    }
    __syncthreads();
    if (tid == 0) {
        float f[QN];
        float m = -INFINITY;
#pragma unroll
        for (int q = 0; q < QN; ++q) {
            f[q] = red[q][0] + red[q][1] + red[q][2] + red[q][3] + bf[0];
            m = fmaxf(m, f[q]);
        }
        float ssum = 0.f;
#pragma unroll
        for (int q = 0; q < QN; ++q) { f[q] = __expf(f[q] - m); ssum += f[q]; }
        const float inv = 1.f / ssum;
#pragma unroll
        for (int q = 0; q < QN; ++q) fwq[q] = f[q] * inv;
    }
    __syncthreads();

    // --- out[n][d] = sum_q pt[q][d] * fw[q] ---
    float o0 = 0.f, o1 = 0.f;
#pragma unroll
    for (int q = 0; q < QN; ++q) {
        const float w = fwq[q];
        o0 += pt[q][0] * w;
        o1 += pt[q][1] * w;
    }
    *(float2*)&out[(size_t)n * DD + d0] = make_float2(o0, o1);
}

// ---------------------------------------------------------------------------
extern "C" void kernel_launch(void* const* d_in, const int* in_sizes, int n_in,
                              void* d_out, int out_size, void* d_ws, size_t ws_size,
                              hipStream_t stream)
{
    const float* patch   = (const float*)d_in[0];
    const float* query   = (const float*)d_in[1];
    const float* Wk      = (const float*)d_in[2];
    const float* bk      = (const float*)d_in[3];
    const float* Wv      = (const float*)d_in[4];
    const float* bv      = (const float*)d_in[5];
    const float* Wf      = (const float*)d_in[6];
    const float* bf      = (const float*)d_in[7];
    const int*   indices = (const int*)d_in[8];
    const void*  pmask   = d_in[9];
    float* out = (float*)d_out;

    // workspace layout (floats): Vp_ext | S | A | c0   (~8.7 MB total)
    float* ws = (float*)d_ws;
    float* Vp = ws;                              // MEXT * D
    float* S  = Vp + (size_t)MEXT * DD;          // MEXT * QN
    float* A  = S  + (size_t)MEXT * QN;          // QN * D
    float* c0 = A  + (size_t)QN * DD;            // QN

    k1_A     <<<dim3(DD + QN), dim3(64), 0, stream>>>(query, Wk, bk, A, c0);
    k2_gemm  <<<dim3(DD / BN, (MEXT + BM - 1) / BM), dim3(256), 0, stream>>>(patch, query, Wv, bv, Vp);
    k3_scores<<<dim3((MEXT + 3) / 4), dim3(256), 0, stream>>>(patch, query, A, c0, S);
    k4_agg   <<<dim3(NGRP), dim3(256), 0, stream>>>(Vp, S, indices, pmask, Wf, bf, out);
}

// Round 2
// 132.649 us; speedup vs baseline: 1.3204x; 1.3204x over previous
//
#include <hip/hip_runtime.h>
#include <hip/hip_bf16.h>
#include <math.h>

// Problem constants: B=32, L=128, D=512, Qn=16, N=512, P=64
#define DD    512
#define QN    16
#define NTOK  4096
#define MEXT  4112           // NTOK + QN
#define MPAD  4224           // 33 * 128
#define NGRP  512
#define PP    64
#define NB    640            // padded B rows: 512 Wv cols + 16 score cols + pad
#define SCALE 0.04419417382415922f   // 1/sqrt(512)

typedef __bf16 bf16x8 __attribute__((ext_vector_type(8)));
typedef float  f32x4  __attribute__((ext_vector_type(4)));

static __device__ __forceinline__ ushort f2bf(float f) {
    __hip_bfloat16 h = __float2bfloat16(f);
    return *reinterpret_cast<ushort*>(&h);
}

// ---------------------------------------------------------------------------
// K1: A[q][e] = sum_d Wk[e][d] * Q0[q][d]  (fp32), c0[q] = bk . Q0[q]
// ---------------------------------------------------------------------------
__global__ __launch_bounds__(64) void k1_A(
    const float* __restrict__ query, const float* __restrict__ Wk,
    const float* __restrict__ bk, float* __restrict__ A, float* __restrict__ c0)
{
    const int e = blockIdx.x;
    const int lane = threadIdx.x;
    if (e < DD) {
        float x[8];
#pragma unroll
        for (int j = 0; j < 8; ++j) x[j] = Wk[e * DD + j * 64 + lane];
        for (int q = 0; q < QN; ++q) {
            float s = 0.f;
#pragma unroll
            for (int j = 0; j < 8; ++j) s += x[j] * query[q * DD + j * 64 + lane];
#pragma unroll
            for (int off = 32; off > 0; off >>= 1) s += __shfl_down(s, off, 64);
            if (lane == 0) A[q * DD + e] = s;
        }
    } else {
        const int q = e - DD;
        float s = 0.f;
#pragma unroll
        for (int j = 0; j < 8; ++j)
            s += bk[j * 64 + lane] * query[q * DD + j * 64 + lane];
#pragma unroll
        for (int off = 32; off > 0; off >>= 1) s += __shfl_down(s, off, 64);
        if (lane == 0) c0[q] = s;
    }
}

// ---------------------------------------------------------------------------
// K_pack: build bf16 operands for the fused MFMA GEMM.
//   Xb [MPAD][512]  = [patch ; Q0 ; zeros]           (bf16)
//   Bb [NB][512]    = rows 0..511:  Wv^T (transposed via LDS tile)
//                     rows 512..527: A (q-major, already k-contiguous)
//                     rows 528..639: zeros
// Region split by blockIdx.x: [0,1056) X-cast, [1056,1120) Wv transpose,
// [1120,1124) A-cast, [1124,1152) zero-fill.
// ---------------------------------------------------------------------------
__global__ __launch_bounds__(256) void k_pack(
    const float* __restrict__ patch, const float* __restrict__ query,
    const float* __restrict__ Wv, const float* __restrict__ Afp,
    ushort* __restrict__ Xb, ushort* __restrict__ Bb)
{
    __shared__ float T[64][65];
    const int b = blockIdx.x;
    const int tid = threadIdx.x;
    if (b < 1056) {                       // X cast: 4224*512 elems, 8/thread
        const int e0 = b * 2048 + tid * 8;
        const int row = e0 >> 9, c = e0 & 511;
        float v[8];
        if (row < NTOK) {
            const float4 a0 = *(const float4*)&patch[(size_t)row * DD + c];
            const float4 a1 = *(const float4*)&patch[(size_t)row * DD + c + 4];
            v[0]=a0.x; v[1]=a0.y; v[2]=a0.z; v[3]=a0.w;
            v[4]=a1.x; v[5]=a1.y; v[6]=a1.z; v[7]=a1.w;
        } else if (row < MEXT) {
            const float4 a0 = *(const float4*)&query[(size_t)(row - NTOK) * DD + c];
            const float4 a1 = *(const float4*)&query[(size_t)(row - NTOK) * DD + c + 4];
            v[0]=a0.x; v[1]=a0.y; v[2]=a0.z; v[3]=a0.w;
            v[4]=a1.x; v[5]=a1.y; v[6]=a1.z; v[7]=a1.w;
        } else {
#pragma unroll
            for (int j = 0; j < 8; ++j) v[j] = 0.f;
        }
        ushort o[8];
#pragma unroll
        for (int j = 0; j < 8; ++j) o[j] = f2bf(v[j]);
        *(uint4*)&Xb[e0] = *(const uint4*)o;
    } else if (b < 1120) {                // Wv transpose, 64x64 tile per block
        const int t = b - 1056;
        const int k0 = (t >> 3) * 64, n0 = (t & 7) * 64;
#pragma unroll
        for (int j = 0; j < 16; ++j) {
            const int idx = tid + j * 256;
            const int r = idx >> 6, c = idx & 63;
            T[r][c] = Wv[(size_t)(k0 + r) * DD + n0 + c];
        }
        __syncthreads();
#pragma unroll
        for (int j = 0; j < 16; ++j) {
            const int idx = tid + j * 256;
            const int r = idx >> 6, c = idx & 63;
            Bb[(size_t)(n0 + r) * DD + k0 + c] = f2bf(T[c][r]);
        }
    } else if (b < 1124) {                // A cast: 16*512 elems
        const int e0 = (b - 1120) * 2048 + tid * 8;
        ushort o[8];
#pragma unroll
        for (int j = 0; j < 8; ++j) o[j] = f2bf(Afp[e0 + j]);
        *(uint4*)&Bb[(size_t)DD * DD + e0] = *(const uint4*)o;
    } else {                              // zero rows 528..639
        const int e0 = (b - 1124) * 2048 + tid * 8;
        *(uint4*)&Bb[(size_t)528 * DD + e0] = make_uint4(0, 0, 0, 0);
    }
}

// ---------------------------------------------------------------------------
// K2: fused MFMA GEMM  C[4112 x 640] = Xb @ Bb^T  (Bb stored [n][k])
//   cols 0..511  -> Vp  (+ bv)
//   cols 512..527-> S   ((acc + c0) * SCALE)
// 128x128 block tile, 256 thr (4 waves, 64x64 each), BK=64, bf16 16x16x32 MFMA
// ---------------------------------------------------------------------------
__global__ __launch_bounds__(256) void k2_mfma(
    const ushort* __restrict__ Xb, const ushort* __restrict__ Bb,
    const float* __restrict__ bv, const float* __restrict__ c0,
    float* __restrict__ Vp, float* __restrict__ S)
{
    __shared__ __align__(16) ushort Xs[128][72];   // +8 pad: 144B row stride
    __shared__ __align__(16) ushort Bs[128][72];
    const int tid = threadIdx.x;
    const int rowBase = blockIdx.y * 128;
    const int colBase = blockIdx.x * 128;
    const int wave = tid >> 6, lane = tid & 63;
    const int wm = (wave >> 1) * 64, wn = (wave & 1) * 64;
    const int lr = lane & 15;
    const int quad = lane >> 4;

    f32x4 acc[4][4];
    const f32x4 zero = {0.f, 0.f, 0.f, 0.f};
#pragma unroll
    for (int i = 0; i < 4; ++i)
#pragma unroll
        for (int j = 0; j < 4; ++j) acc[i][j] = zero;

    for (int k0 = 0; k0 < DD; k0 += 64) {
#pragma unroll
        for (int i = 0; i < 4; ++i) {
            const int ch = tid + i * 256;          // 1024 chunks per operand
            const int r = ch >> 3, cc = (ch & 7) * 8;
            *(uint4*)&Xs[r][cc] = *(const uint4*)&Xb[(size_t)(rowBase + r) * DD + k0 + cc];
            *(uint4*)&Bs[r][cc] = *(const uint4*)&Bb[(size_t)(colBase + r) * DD + k0 + cc];
        }
        __syncthreads();
#pragma unroll
        for (int kc = 0; kc < 2; ++kc) {
            bf16x8 af[4], bfr[4];
#pragma unroll
            for (int t = 0; t < 4; ++t) {
                af[t]  = *(const bf16x8*)&Xs[wm + t * 16 + lr][kc * 32 + quad * 8];
                bfr[t] = *(const bf16x8*)&Bs[wn + t * 16 + lr][kc * 32 + quad * 8];
            }
#pragma unroll
            for (int mt = 0; mt < 4; ++mt)
#pragma unroll
                for (int nt = 0; nt < 4; ++nt)
                    acc[mt][nt] = __builtin_amdgcn_mfma_f32_16x16x32_bf16(
                        af[mt], bfr[nt], acc[mt][nt], 0, 0, 0);
        }
        __syncthreads();
    }

    // epilogue: C/D layout col = lane&15, row = quad*4 + r (verified m89/m91)
#pragma unroll
    for (int nt = 0; nt < 4; ++nt) {
        const int col = colBase + wn + nt * 16 + lr;
        const bool isV = (col < DD);
        const bool isS = (col >= DD) && (col < DD + QN);
        const float badd = isV ? bv[col] : (isS ? c0[col - DD] : 0.f);
#pragma unroll
        for (int mt = 0; mt < 4; ++mt) {
#pragma unroll
            for (int r = 0; r < 4; ++r) {
                const int row = rowBase + wm + mt * 16 + quad * 4 + r;
                if (row < MEXT) {
                    const float v = acc[mt][nt][r];
                    if (isV)      Vp[(size_t)row * DD + col] = v + badd;
                    else if (isS) S[row * QN + (col - DD)] = (v + badd) * SCALE;
                }
            }
        }
    }
}

// ---------------------------------------------------------------------------
// K4: per-group aggregation, compacted active-p list + unroll-4 gather
// ---------------------------------------------------------------------------
__global__ __launch_bounds__(256) void k4_agg(
    const float* __restrict__ Vp,      // MEXT x D (rows >= NTOK are VQ)
    const float* __restrict__ S,       // MEXT x QN
    const int* __restrict__ indices,
    const void* __restrict__ pmask,
    const float* __restrict__ Wf, const float* __restrict__ bf,
    float* __restrict__ out)
{
    __shared__ int   idxs[PP];
    __shared__ int   mval[PP];
    __shared__ int   cidx[PP + 4];
    __shared__ int   cp[PP + 4];
    __shared__ float sc[QN][PP + 2];   // col0=self, 1..64=gathered, 65=zero pad
    __shared__ float red[QN][4];
    __shared__ float fwq[QN];
    __shared__ int   cntS;

    const int n = blockIdx.x;
    const int tid = threadIdx.x;

    // pos_mask storage-width detection (wave-uniform)
    const unsigned int* mw = (const unsigned int*)pmask;
    bool four = true;
#pragma unroll
    for (int i = 0; i < 16; ++i) {
        const unsigned int v = mw[i];
        four = four && (v == 0u || v == 1u || v == 0x3F800000u);
    }

    if (tid < PP) {
        idxs[tid] = indices[n * PP + tid];
        int mv;
        if (four) mv = (mw[n * PP + tid] != 0u);
        else      mv = (((const unsigned char*)pmask)[n * PP + tid] != 0);
        mval[tid] = mv;
        const bool a = (mv != 0);
        const unsigned long long m = __ballot(a);
        const int pos = __popcll(m & ((1ull << tid) - 1ull));
        if (a) { cidx[pos] = idxs[tid]; cp[pos] = tid; }
        if (tid == 0) cntS = (int)__popcll(m);
    }
    __syncthreads();

    // gather scores
    for (int e = tid; e < QN * PP; e += 256) {
        const int q = e & (QN - 1), p = e >> 4;
        sc[q][p + 1] = mval[p] ? S[idxs[p] * QN + q] : -INFINITY;
    }
    if (tid < QN) sc[tid][0] = S[(NTOK + tid) * QN + tid];   // s_self[q]
    __syncthreads();

    if (tid < 4) { cidx[cntS + tid] = 0; cp[cntS + tid] = PP; }  // pad entries
    if (tid < QN) {                                  // softmax over 65 per q
        const int q = tid;
        float m = -INFINITY;
        for (int j = 0; j <= PP; ++j) m = fmaxf(m, sc[q][j]);
        float s = 0.f;
        for (int j = 0; j <= PP; ++j) { const float e = __expf(sc[q][j] - m); sc[q][j] = e; s += e; }
        const float inv = 1.f / s;
        for (int j = 0; j <= PP; ++j) sc[q][j] *= inv;
        sc[q][PP + 1] = 0.f;                         // pad weight = 0
    }
    __syncthreads();

    const int cnt4 = (cntS + 3) & ~3;
    const int d0 = tid * 2;
    float pt[QN][2];
#pragma unroll
    for (int q = 0; q < QN; ++q) {
        const float w0 = sc[q][0];
        const float2 vq = *(const float2*)&Vp[(size_t)(NTOK + q) * DD + d0];
        pt[q][0] = w0 * vq.x;
        pt[q][1] = w0 * vq.y;
    }
    for (int j0 = 0; j0 < cnt4; j0 += 4) {
        const float2 v0 = *(const float2*)&Vp[(size_t)cidx[j0 + 0] * DD + d0];
        const float2 v1 = *(const float2*)&Vp[(size_t)cidx[j0 + 1] * DD + d0];
        const float2 v2 = *(const float2*)&Vp[(size_t)cidx[j0 + 2] * DD + d0];
        const float2 v3 = *(const float2*)&Vp[(size_t)cidx[j0 + 3] * DD + d0];
        const int p0 = cp[j0], p1 = cp[j0 + 1], p2 = cp[j0 + 2], p3 = cp[j0 + 3];
#pragma unroll
        for (int q = 0; q < QN; ++q) {
            const float w0 = sc[q][p0 + 1], w1 = sc[q][p1 + 1];
            const float w2 = sc[q][p2 + 1], w3 = sc[q][p3 + 1];
            pt[q][0] += w0 * v0.x + w1 * v1.x + w2 * v2.x + w3 * v3.x;
            pt[q][1] += w0 * v0.y + w1 * v1.y + w2 * v2.y + w3 * v3.y;
        }
    }

    // fusion logits f[q] = pt[q,:] . Wf + bf
    const float wf0 = Wf[d0], wf1 = Wf[d0 + 1];
    const int wid = tid >> 6, lane = tid & 63;
#pragma unroll
    for (int q = 0; q < QN; ++q) {
        float s = pt[q][0] * wf0 + pt[q][1] * wf1;
#pragma unroll
        for (int off = 32; off > 0; off >>= 1) s += __shfl_down(s, off, 64);
        if (lane == 0) red[q][wid] = s;
    }
    __syncthreads();
    if (tid == 0) {
        float f[QN];
        float m = -INFINITY;
#pragma unroll
        for (int q = 0; q < QN; ++q) {
            f[q] = red[q][0] + red[q][1] + red[q][2] + red[q][3] + bf[0];
            m = fmaxf(m, f[q]);
        }
        float ssum = 0.f;
#pragma unroll
        for (int q = 0; q < QN; ++q) { f[q] = __expf(f[q] - m); ssum += f[q]; }
        const float inv = 1.f / ssum;
#pragma unroll
        for (int q = 0; q < QN; ++q) fwq[q] = f[q] * inv;
    }
    __syncthreads();

    float o0 = 0.f, o1 = 0.f;
#pragma unroll
    for (int q = 0; q < QN; ++q) {
        const float w = fwq[q];
        o0 += pt[q][0] * w;
        o1 += pt[q][1] * w;
    }
    *(float2*)&out[(size_t)n * DD + d0] = make_float2(o0, o1);
}

// ---------------------------------------------------------------------------
extern "C" void kernel_launch(void* const* d_in, const int* in_sizes, int n_in,
                              void* d_out, int out_size, void* d_ws, size_t ws_size,
                              hipStream_t stream)
{
    const float* patch   = (const float*)d_in[0];
    const float* query   = (const float*)d_in[1];
    const float* Wk      = (const float*)d_in[2];
    const float* bk      = (const float*)d_in[3];
    const float* Wv      = (const float*)d_in[4];
    const float* bv      = (const float*)d_in[5];
    const float* Wf      = (const float*)d_in[6];
    const float* bf      = (const float*)d_in[7];
    const int*   indices = (const int*)d_in[8];
    const void*  pmask   = d_in[9];
    float* out = (float*)d_out;

    // workspace: Vp f32[MEXT*DD] | S f32[MEXT*QN] | A f32[QN*DD] | c0 f32[16]
    //            | Xb bf16[MPAD*DD] | Bb bf16[NB*DD]
    float* ws = (float*)d_ws;
    float* Vp = ws;
    float* S  = Vp + (size_t)MEXT * DD;
    float* A  = S  + (size_t)MEXT * QN;
    float* c0 = A  + (size_t)QN * DD;
    ushort* Xb = (ushort*)(c0 + 16);
    ushort* Bb = Xb + (size_t)MPAD * DD;

    k1_A   <<<dim3(DD + QN), dim3(64), 0, stream>>>(query, Wk, bk, A, c0);
    k_pack <<<dim3(1152), dim3(256), 0, stream>>>(patch, query, Wv, A, Xb, Bb);
    k2_mfma<<<dim3(5, 33), dim3(256), 0, stream>>>(Xb, Bb, bv, c0, Vp, S);
    k4_agg <<<dim3(NGRP), dim3(256), 0, stream>>>(Vp, S, indices, pmask, Wf, bf, out);
}

// Round 4
// 124.022 us; speedup vs baseline: 1.4122x; 1.0696x over previous
//
#include <hip/hip_runtime.h>
#include <hip/hip_bf16.h>
#include <math.h>

// Problem constants: B=32, L=128, D=512, Qn=16, N=512, P=64
#define DD    512
#define QN    16
#define NTOK  4096
#define MEXT  4112           // NTOK + QN
#define MPAD  4224           // 33 * 128
#define NGRP  512
#define PP    64
#define NB    640            // padded B rows: 512 Wv cols + 16 score cols + pad
#define SCALE 0.04419417382415922f   // 1/sqrt(512)

typedef __bf16 bf16x8 __attribute__((ext_vector_type(8)));
typedef float  f32x4  __attribute__((ext_vector_type(4)));

static __device__ __forceinline__ ushort f2bf(float f) {
    __hip_bfloat16 h = __float2bfloat16(f);
    return *reinterpret_cast<ushort*>(&h);
}

// ---------------------------------------------------------------------------
// pack_all: one kernel, block-range dispatch (no cross-range dependencies).
//  [0,1056)    : Xb = bf16([patch ; Q0 ; zeros])              (4224 x 512)
//  [1056,1120) : Bb rows 0..511   = bf16(Wv^T)  (64x64 LDS-tile transpose)
//  [1120,1148) : Bb rows 528..639 = 0
//  [1148,1280) : Bb rows 512..527 = bf16(Wk @ Q0^T), + c0[q] = bk.Q0[q]
// ---------------------------------------------------------------------------
__global__ __launch_bounds__(256) void pack_all(
    const float* __restrict__ patch, const float* __restrict__ query,
    const float* __restrict__ Wv, const float* __restrict__ Wk,
    const float* __restrict__ bk,
    ushort* __restrict__ Xb, ushort* __restrict__ Bb, float* __restrict__ c0)
{
    __shared__ float T[64][65];
    const int b = blockIdx.x;
    const int tid = threadIdx.x;
    if (b < 1056) {                       // X cast: 8 elems/thread
        const int e0 = b * 2048 + tid * 8;
        const int row = e0 >> 9, c = e0 & 511;
        float v[8];
        if (row < NTOK) {
            const float4 a0 = *(const float4*)&patch[(size_t)row * DD + c];
            const float4 a1 = *(const float4*)&patch[(size_t)row * DD + c + 4];
            v[0]=a0.x; v[1]=a0.y; v[2]=a0.z; v[3]=a0.w;
            v[4]=a1.x; v[5]=a1.y; v[6]=a1.z; v[7]=a1.w;
        } else if (row < MEXT) {
            const float4 a0 = *(const float4*)&query[(size_t)(row - NTOK) * DD + c];
            const float4 a1 = *(const float4*)&query[(size_t)(row - NTOK) * DD + c + 4];
            v[0]=a0.x; v[1]=a0.y; v[2]=a0.z; v[3]=a0.w;
            v[4]=a1.x; v[5]=a1.y; v[6]=a1.z; v[7]=a1.w;
        } else {
#pragma unroll
            for (int j = 0; j < 8; ++j) v[j] = 0.f;
        }
        ushort o[8];
#pragma unroll
        for (int j = 0; j < 8; ++j) o[j] = f2bf(v[j]);
        *(uint4*)&Xb[e0] = *(const uint4*)o;
    } else if (b < 1120) {                // Wv transpose, 64x64 tile
        const int t = b - 1056;
        const int k0 = (t >> 3) * 64, n0 = (t & 7) * 64;
#pragma unroll
        for (int j = 0; j < 16; ++j) {
            const int idx = tid + j * 256;
            const int r = idx >> 6, c = idx & 63;
            T[r][c] = Wv[(size_t)(k0 + r) * DD + n0 + c];
        }
        __syncthreads();
#pragma unroll
        for (int j = 0; j < 16; ++j) {
            const int idx = tid + j * 256;
            const int r = idx >> 6, c = idx & 63;
            Bb[(size_t)(n0 + r) * DD + k0 + c] = f2bf(T[c][r]);
        }
    } else if (b < 1148) {                // zero rows 528..639
        const int e0 = (b - 1120) * 2048 + tid * 8;
        *(uint4*)&Bb[(size_t)528 * DD + e0] = make_uint4(0, 0, 0, 0);
    } else {                              // A (score B-rows) + c0
        const int wave = tid >> 6, lane = tid & 63;
        const int g = (b - 1148) * 4 + wave;
        if (g < DD) {
            const int e = g;
            float x[8];
#pragma unroll
            for (int j = 0; j < 8; ++j) x[j] = Wk[e * DD + j * 64 + lane];
            for (int q = 0; q < QN; ++q) {
                float s = 0.f;
#pragma unroll
                for (int j = 0; j < 8; ++j) s += x[j] * query[q * DD + j * 64 + lane];
#pragma unroll
                for (int off = 32; off > 0; off >>= 1) s += __shfl_down(s, off, 64);
                if (lane == 0) Bb[(size_t)(DD + q) * DD + e] = f2bf(s);
            }
        } else {
            const int q = g - DD;
            float s = 0.f;
#pragma unroll
            for (int j = 0; j < 8; ++j)
                s += bk[j * 64 + lane] * query[q * DD + j * 64 + lane];
#pragma unroll
            for (int off = 32; off > 0; off >>= 1) s += __shfl_down(s, off, 64);
            if (lane == 0) c0[q] = s;
        }
    }
}

// ---------------------------------------------------------------------------
// K2: fused MFMA GEMM  C[4112 x 640] = Xb @ Bb^T  (Bb stored [n][k])
//   cols 0..511   -> Vp (+ bv);  cols 512..527 -> S ((acc + c0) * SCALE)
// 128x64 block tile, 256 thr (4 waves: 2x2 over rows x cols, 64x32 each),
// BK=64, bf16 16x16x32 MFMA. grid (10, 33) = 330 blocks.
// ---------------------------------------------------------------------------
__global__ __launch_bounds__(256) void k2_mfma(
    const ushort* __restrict__ Xb, const ushort* __restrict__ Bb,
    const float* __restrict__ bv, const float* __restrict__ c0,
    float* __restrict__ Vp, float* __restrict__ S)
{
    __shared__ __align__(16) ushort Xs[128][72];   // +8 pad (m97 pattern)
    __shared__ __align__(16) ushort Bs[64][72];
    const int tid = threadIdx.x;
    const int rowBase = blockIdx.y * 128;
    const int colBase = blockIdx.x * 64;
    const int wave = tid >> 6, lane = tid & 63;
    const int wm = (wave >> 1) * 64, wn = (wave & 1) * 32;
    const int lr = lane & 15;
    const int quad = lane >> 4;

    f32x4 acc[4][2];
    const f32x4 zero = {0.f, 0.f, 0.f, 0.f};
#pragma unroll
    for (int i = 0; i < 4; ++i) { acc[i][0] = zero; acc[i][1] = zero; }

    for (int k0 = 0; k0 < DD; k0 += 64) {
#pragma unroll
        for (int i = 0; i < 4; ++i) {          // X: 1024 16B chunks
            const int ch = tid + i * 256;
            const int r = ch >> 3, cc = (ch & 7) * 8;
            *(uint4*)&Xs[r][cc] = *(const uint4*)&Xb[(size_t)(rowBase + r) * DD + k0 + cc];
        }
#pragma unroll
        for (int i = 0; i < 2; ++i) {          // B: 512 16B chunks
            const int ch = tid + i * 256;
            const int r = ch >> 3, cc = (ch & 7) * 8;
            *(uint4*)&Bs[r][cc] = *(const uint4*)&Bb[(size_t)(colBase + r) * DD + k0 + cc];
        }
        __syncthreads();
#pragma unroll
        for (int kc = 0; kc < 2; ++kc) {
            bf16x8 af[4], bfr[2];
#pragma unroll
            for (int t = 0; t < 4; ++t)
                af[t] = *(const bf16x8*)&Xs[wm + t * 16 + lr][kc * 32 + quad * 8];
#pragma unroll
            for (int u = 0; u < 2; ++u)
                bfr[u] = *(const bf16x8*)&Bs[wn + u * 16 + lr][kc * 32 + quad * 8];
#pragma unroll
            for (int mt = 0; mt < 4; ++mt)
#pragma unroll
                for (int nt = 0; nt < 2; ++nt)
                    acc[mt][nt] = __builtin_amdgcn_mfma_f32_16x16x32_bf16(
                        af[mt], bfr[nt], acc[mt][nt], 0, 0, 0);
        }
        __syncthreads();
    }

    // epilogue: C/D layout col = lane&15, row = quad*4 + r (m89/m91)
#pragma unroll
    for (int nt = 0; nt < 2; ++nt) {
        const int col = colBase + wn + nt * 16 + lr;
        const bool isV = (col < DD);
        const bool isS = (col >= DD) && (col < DD + QN);
        const float badd = isV ? bv[col] : (isS ? c0[col - DD] : 0.f);
#pragma unroll
        for (int mt = 0; mt < 4; ++mt) {
#pragma unroll
            for (int r = 0; r < 4; ++r) {
                const int row = rowBase + wm + mt * 16 + quad * 4 + r;
                if (row < MEXT) {
                    const float v = acc[mt][nt][r];
                    if (isV)      Vp[(size_t)row * DD + col] = v + badd;
                    else if (isS) S[row * QN + (col - DD)] = (v + badd) * SCALE;
                }
            }
        }
    }
}

// ---------------------------------------------------------------------------
// K4: per-group aggregation. Weights stored p-major (scT[p][q]) so the gather
// loop reads 16 broadcast float4 LDS reads per 4-p iteration (conflict-free).
// ---------------------------------------------------------------------------
__global__ __launch_bounds__(256) void k4_agg(
    const float* __restrict__ Vp,      // MEXT x D (rows >= NTOK are VQ)
    const float* __restrict__ S,       // MEXT x QN
    const int* __restrict__ indices,
    const void* __restrict__ pmask,
    const float* __restrict__ Wf, const float* __restrict__ bf,
    float* __restrict__ out)
{
    __shared__ int   idxs[PP];
    __shared__ int   mval[PP];
    __shared__ int   cidx[PP + 4];
    __shared__ int   cp[PP + 4];
    __shared__ float scT[PP + 2][QN];  // row0=self, 1..64=gathered, 65=zero pad
    __shared__ float red[QN][4];
    __shared__ float fwq[QN];
    __shared__ int   cntS;

    const int n = blockIdx.x;
    const int tid = threadIdx.x;

    // pos_mask storage-width detection (wave-uniform)
    const unsigned int* mw = (const unsigned int*)pmask;
    bool four = true;
#pragma unroll
    for (int i = 0; i < 16; ++i) {
        const unsigned int v = mw[i];
        four = four && (v == 0u || v == 1u || v == 0x3F800000u);
    }

    if (tid < PP) {
        idxs[tid] = indices[n * PP + tid];
        int mv;
        if (four) mv = (mw[n * PP + tid] != 0u);
        else      mv = (((const unsigned char*)pmask)[n * PP + tid] != 0);
        mval[tid] = mv;
        const bool a = (mv != 0);
        const unsigned long long m = __ballot(a);
        const int pos = __popcll(m & ((1ull << tid) - 1ull));
        if (a) { cidx[pos] = idxs[tid]; cp[pos] = tid; }
        if (tid == 0) cntS = (int)__popcll(m);
    }
    __syncthreads();

    // gather scores (p-major) — FULL 1024-entry fill (R3 bug: only 256 filled)
    for (int e = tid; e < QN * PP; e += 256) {
        const int p = e >> 4, q = e & 15;
        scT[p + 1][q] = mval[p] ? S[idxs[p] * QN + q] : -INFINITY;
    }
    if (tid < QN) scT[0][tid] = S[(NTOK + tid) * QN + tid];   // s_self[q]
    __syncthreads();

    if (tid < 4) { cidx[cntS + tid] = 0; cp[cntS + tid] = PP; }  // pad entries
    if (tid < QN) {                                  // softmax over 65 per q
        const int q = tid;
        float m = -INFINITY;
        for (int j = 0; j <= PP; ++j) m = fmaxf(m, scT[j][q]);
        float s = 0.f;
        for (int j = 0; j <= PP; ++j) { const float e = __expf(scT[j][q] - m); scT[j][q] = e; s += e; }
        const float inv = 1.f / s;
        for (int j = 0; j <= PP; ++j) scT[j][q] *= inv;
        scT[PP + 1][q] = 0.f;                        // pad weight = 0
    }
    __syncthreads();

    const int cnt4 = (cntS + 3) & ~3;
    const int d0 = tid * 2;
    float pt[QN][2];
#pragma unroll
    for (int q = 0; q < QN; ++q) {
        const float w0 = scT[0][q];
        const float2 vq = *(const float2*)&Vp[(size_t)(NTOK + q) * DD + d0];
        pt[q][0] = w0 * vq.x;
        pt[q][1] = w0 * vq.y;
    }
    for (int j0 = 0; j0 < cnt4; j0 += 4) {
        float2 v[4]; int p[4];
#pragma unroll
        for (int pi = 0; pi < 4; ++pi) {
            v[pi] = *(const float2*)&Vp[(size_t)cidx[j0 + pi] * DD + d0];
            p[pi] = cp[j0 + pi] + 1;
        }
#pragma unroll
        for (int pi = 0; pi < 4; ++pi) {
            const float4 wa = *(const float4*)&scT[p[pi]][0];
            const float4 wb = *(const float4*)&scT[p[pi]][4];
            const float4 wc = *(const float4*)&scT[p[pi]][8];
            const float4 wd = *(const float4*)&scT[p[pi]][12];
            const float vx = v[pi].x, vy = v[pi].y;
            pt[ 0][0] += wa.x*vx; pt[ 0][1] += wa.x*vy;
            pt[ 1][0] += wa.y*vx; pt[ 1][1] += wa.y*vy;
            pt[ 2][0] += wa.z*vx; pt[ 2][1] += wa.z*vy;
            pt[ 3][0] += wa.w*vx; pt[ 3][1] += wa.w*vy;
            pt[ 4][0] += wb.x*vx; pt[ 4][1] += wb.x*vy;
            pt[ 5][0] += wb.y*vx; pt[ 5][1] += wb.y*vy;
            pt[ 6][0] += wb.z*vx; pt[ 6][1] += wb.z*vy;
            pt[ 7][0] += wb.w*vx; pt[ 7][1] += wb.w*vy;
            pt[ 8][0] += wc.x*vx; pt[ 8][1] += wc.x*vy;
            pt[ 9][0] += wc.y*vx; pt[ 9][1] += wc.y*vy;
            pt[10][0] += wc.z*vx; pt[10][1] += wc.z*vy;
            pt[11][0] += wc.w*vx; pt[11][1] += wc.w*vy;
            pt[12][0] += wd.x*vx; pt[12][1] += wd.x*vy;
            pt[13][0] += wd.y*vx; pt[13][1] += wd.y*vy;
            pt[14][0] += wd.z*vx; pt[14][1] += wd.z*vy;
            pt[15][0] += wd.w*vx; pt[15][1] += wd.w*vy;
        }
    }

    // fusion logits f[q] = pt[q,:] . Wf + bf
    const float wf0 = Wf[d0], wf1 = Wf[d0 + 1];
    const int wid = tid >> 6, lane = tid & 63;
#pragma unroll
    for (int q = 0; q < QN; ++q) {
        float s = pt[q][0] * wf0 + pt[q][1] * wf1;
#pragma unroll
        for (int off = 32; off > 0; off >>= 1) s += __shfl_down(s, off, 64);
        if (lane == 0) red[q][wid] = s;
    }
    __syncthreads();
    if (tid == 0) {
        float f[QN];
        float m = -INFINITY;
#pragma unroll
        for (int q = 0; q < QN; ++q) {
            f[q] = red[q][0] + red[q][1] + red[q][2] + red[q][3] + bf[0];
            m = fmaxf(m, f[q]);
        }
        float ssum = 0.f;
#pragma unroll
        for (int q = 0; q < QN; ++q) { f[q] = __expf(f[q] - m); ssum += f[q]; }
        const float inv = 1.f / ssum;
#pragma unroll
        for (int q = 0; q < QN; ++q) fwq[q] = f[q] * inv;
    }
    __syncthreads();

    float o0 = 0.f, o1 = 0.f;
#pragma unroll
    for (int q = 0; q < QN; ++q) {
        const float w = fwq[q];
        o0 += pt[q][0] * w;
        o1 += pt[q][1] * w;
    }
    *(float2*)&out[(size_t)n * DD + d0] = make_float2(o0, o1);
}

// ---------------------------------------------------------------------------
extern "C" void kernel_launch(void* const* d_in, const int* in_sizes, int n_in,
                              void* d_out, int out_size, void* d_ws, size_t ws_size,
                              hipStream_t stream)
{
    const float* patch   = (const float*)d_in[0];
    const float* query   = (const float*)d_in[1];
    const float* Wk      = (const float*)d_in[2];
    const float* bk      = (const float*)d_in[3];
    const float* Wv      = (const float*)d_in[4];
    const float* bv      = (const float*)d_in[5];
    const float* Wf      = (const float*)d_in[6];
    const float* bf      = (const float*)d_in[7];
    const int*   indices = (const int*)d_in[8];
    const void*  pmask   = d_in[9];
    float* out = (float*)d_out;

    // ws: Vp f32[MEXT*DD] | S f32[MEXT*QN] | c0 f32[16] | Xb bf16[MPAD*DD]
    //     | Bb bf16[NB*DD]      (~13.7 MB of the 256 MiB ws)
    float* ws = (float*)d_ws;
    float* Vp = ws;
    float* S  = Vp + (size_t)MEXT * DD;
    float* c0 = S  + (size_t)MEXT * QN;
    ushort* Xb = (ushort*)(c0 + 16);
    ushort* Bb = Xb + (size_t)MPAD * DD;

    pack_all<<<dim3(1280), dim3(256), 0, stream>>>(patch, query, Wv, Wk, bk, Xb, Bb, c0);
    k2_mfma <<<dim3(10, 33), dim3(256), 0, stream>>>(Xb, Bb, bv, c0, Vp, S);
    k4_agg  <<<dim3(NGRP), dim3(256), 0, stream>>>(Vp, S, indices, pmask, Wf, bf, out);
}

// Round 5
// 123.093 us; speedup vs baseline: 1.4229x; 1.0075x over previous
//
#include <hip/hip_runtime.h>
#include <hip/hip_bf16.h>
#include <math.h>

// Problem constants: B=32, L=128, D=512, Qn=16, N=512, P=64
#define DD    512
#define QN    16
#define NTOK  4096
#define MEXT  4112           // NTOK + QN
#define MPAD  4224           // 66 * 64
#define NGRP  512
#define PP    64
#define NB    640            // padded B rows: 512 Wv cols + 16 score cols + pad
#define SCALE 0.04419417382415922f   // 1/sqrt(512)

typedef __bf16 bf16x8 __attribute__((ext_vector_type(8)));
typedef float  f32x4  __attribute__((ext_vector_type(4)));

static __device__ __forceinline__ ushort f2bf(float f) {
    __hip_bfloat16 h = __float2bfloat16(f);
    return *reinterpret_cast<ushort*>(&h);
}
// unpack 2 packed bf16 (little-endian: low ushort = element 0) to fp32
static __device__ __forceinline__ float2 bfp2f2(unsigned int v) {
    float2 r;
    r.x = __uint_as_float(v << 16);
    r.y = __uint_as_float(v & 0xffff0000u);
    return r;
}

// ---------------------------------------------------------------------------
// pack_all: one kernel, block-range dispatch (no cross-range dependencies).
//  [0,1056)    : Xb = bf16([patch ; Q0 ; zeros])              (4224 x 512)
//  [1056,1120) : Bb rows 0..511   = bf16(Wv^T)  (64x64 LDS-tile transpose)
//  [1120,1148) : Bb rows 528..639 = 0
//  [1148,1280) : Bb rows 512..527 = bf16(Wk @ Q0^T), + c0[q] = bk.Q0[q]
// ---------------------------------------------------------------------------
__global__ __launch_bounds__(256) void pack_all(
    const float* __restrict__ patch, const float* __restrict__ query,
    const float* __restrict__ Wv, const float* __restrict__ Wk,
    const float* __restrict__ bk,
    ushort* __restrict__ Xb, ushort* __restrict__ Bb, float* __restrict__ c0)
{
    __shared__ float T[64][65];
    const int b = blockIdx.x;
    const int tid = threadIdx.x;
    if (b < 1056) {                       // X cast: 8 elems/thread
        const int e0 = b * 2048 + tid * 8;
        const int row = e0 >> 9, c = e0 & 511;
        float v[8];
        if (row < NTOK) {
            const float4 a0 = *(const float4*)&patch[(size_t)row * DD + c];
            const float4 a1 = *(const float4*)&patch[(size_t)row * DD + c + 4];
            v[0]=a0.x; v[1]=a0.y; v[2]=a0.z; v[3]=a0.w;
            v[4]=a1.x; v[5]=a1.y; v[6]=a1.z; v[7]=a1.w;
        } else if (row < MEXT) {
            const float4 a0 = *(const float4*)&query[(size_t)(row - NTOK) * DD + c];
            const float4 a1 = *(const float4*)&query[(size_t)(row - NTOK) * DD + c + 4];
            v[0]=a0.x; v[1]=a0.y; v[2]=a0.z; v[3]=a0.w;
            v[4]=a1.x; v[5]=a1.y; v[6]=a1.z; v[7]=a1.w;
        } else {
#pragma unroll
            for (int j = 0; j < 8; ++j) v[j] = 0.f;
        }
        ushort o[8];
#pragma unroll
        for (int j = 0; j < 8; ++j) o[j] = f2bf(v[j]);
        *(uint4*)&Xb[e0] = *(const uint4*)o;
    } else if (b < 1120) {                // Wv transpose, 64x64 tile
        const int t = b - 1056;
        const int k0 = (t >> 3) * 64, n0 = (t & 7) * 64;
#pragma unroll
        for (int j = 0; j < 16; ++j) {
            const int idx = tid + j * 256;
            const int r = idx >> 6, c = idx & 63;
            T[r][c] = Wv[(size_t)(k0 + r) * DD + n0 + c];
        }
        __syncthreads();
#pragma unroll
        for (int j = 0; j < 16; ++j) {
            const int idx = tid + j * 256;
            const int r = idx >> 6, c = idx & 63;
            Bb[(size_t)(n0 + r) * DD + k0 + c] = f2bf(T[c][r]);
        }
    } else if (b < 1148) {                // zero rows 528..639
        const int e0 = (b - 1120) * 2048 + tid * 8;
        *(uint4*)&Bb[(size_t)528 * DD + e0] = make_uint4(0, 0, 0, 0);
    } else {                              // A (score B-rows) + c0
        const int wave = tid >> 6, lane = tid & 63;
        const int g = (b - 1148) * 4 + wave;
        if (g < DD) {
            const int e = g;
            float x[8];
#pragma unroll
            for (int j = 0; j < 8; ++j) x[j] = Wk[e * DD + j * 64 + lane];
            for (int q = 0; q < QN; ++q) {
                float s = 0.f;
#pragma unroll
                for (int j = 0; j < 8; ++j) s += x[j] * query[q * DD + j * 64 + lane];
#pragma unroll
                for (int off = 32; off > 0; off >>= 1) s += __shfl_down(s, off, 64);
                if (lane == 0) Bb[(size_t)(DD + q) * DD + e] = f2bf(s);
            }
        } else {
            const int q = g - DD;
            float s = 0.f;
#pragma unroll
            for (int j = 0; j < 8; ++j)
                s += bk[j * 64 + lane] * query[q * DD + j * 64 + lane];
#pragma unroll
            for (int off = 32; off > 0; off >>= 1) s += __shfl_down(s, off, 64);
            if (lane == 0) c0[q] = s;
        }
    }
}

// ---------------------------------------------------------------------------
// K2: fused MFMA GEMM  C[4224 x 640] = Xb @ Bb^T  (Bb stored [n][k])
//   cols 0..511   -> VpH bf16 (+ bv);  cols 512..527 -> S fp32 ((acc+c0)*SCALE)
// 64x64 block tile, 256 thr (4 waves: 2x2, each 32x32 via 2x2 MFMA tiles),
// BK=64, bf16 16x16x32 MFMA. grid (10, 66) = 660 blocks (2.6/CU).
// ---------------------------------------------------------------------------
__global__ __launch_bounds__(256) void k2_mfma(
    const ushort* __restrict__ Xb, const ushort* __restrict__ Bb,
    const float* __restrict__ bv, const float* __restrict__ c0,
    ushort* __restrict__ VpH, float* __restrict__ S)
{
    __shared__ __align__(16) ushort Xs[64][72];   // +8 pad (m97 pattern)
    __shared__ __align__(16) ushort Bs[64][72];
    const int tid = threadIdx.x;
    const int rowBase = blockIdx.y * 64;
    const int colBase = blockIdx.x * 64;
    const int wave = tid >> 6, lane = tid & 63;
    const int wm = (wave >> 1) * 32, wn = (wave & 1) * 32;
    const int lr = lane & 15;
    const int quad = lane >> 4;

    f32x4 acc[2][2];
    const f32x4 zero = {0.f, 0.f, 0.f, 0.f};
#pragma unroll
    for (int i = 0; i < 2; ++i) { acc[i][0] = zero; acc[i][1] = zero; }

    for (int k0 = 0; k0 < DD; k0 += 64) {
#pragma unroll
        for (int i = 0; i < 2; ++i) {          // X: 512 16B chunks
            const int ch = tid + i * 256;
            const int r = ch >> 3, cc = (ch & 7) * 8;
            *(uint4*)&Xs[r][cc] = *(const uint4*)&Xb[(size_t)(rowBase + r) * DD + k0 + cc];
        }
#pragma unroll
        for (int i = 0; i < 2; ++i) {          // B: 512 16B chunks
            const int ch = tid + i * 256;
            const int r = ch >> 3, cc = (ch & 7) * 8;
            *(uint4*)&Bs[r][cc] = *(const uint4*)&Bb[(size_t)(colBase + r) * DD + k0 + cc];
        }
        __syncthreads();
#pragma unroll
        for (int kc = 0; kc < 2; ++kc) {
            bf16x8 af[2], bfr[2];
#pragma unroll
            for (int t = 0; t < 2; ++t)
                af[t] = *(const bf16x8*)&Xs[wm + t * 16 + lr][kc * 32 + quad * 8];
#pragma unroll
            for (int u = 0; u < 2; ++u)
                bfr[u] = *(const bf16x8*)&Bs[wn + u * 16 + lr][kc * 32 + quad * 8];
#pragma unroll
            for (int mt = 0; mt < 2; ++mt)
#pragma unroll
                for (int nt = 0; nt < 2; ++nt)
                    acc[mt][nt] = __builtin_amdgcn_mfma_f32_16x16x32_bf16(
                        af[mt], bfr[nt], acc[mt][nt], 0, 0, 0);
        }
        __syncthreads();
    }

    // epilogue: C/D layout col = lane&15, row = quad*4 + r (m89/m91)
#pragma unroll
    for (int nt = 0; nt < 2; ++nt) {
        const int col = colBase + wn + nt * 16 + lr;
        const bool isV = (col < DD);
        const bool isS = (col >= DD) && (col < DD + QN);
        const float badd = isV ? bv[col] : (isS ? c0[col - DD] : 0.f);
#pragma unroll
        for (int mt = 0; mt < 2; ++mt) {
#pragma unroll
            for (int r = 0; r < 4; ++r) {
                const int row = rowBase + wm + mt * 16 + quad * 4 + r;
                if (row < MEXT) {
                    const float v = acc[mt][nt][r];
                    if (isV)      VpH[(size_t)row * DD + col] = f2bf(v + badd);
                    else if (isS) S[row * QN + (col - DD)] = (v + badd) * SCALE;
                }
            }
        }
    }
}

// ---------------------------------------------------------------------------
// K4: per-group aggregation. Vp gathered as bf16 (4.2 MB ~ L2-resident).
// Weights p-major in LDS (scT[p][q]) -> broadcast float4 reads, conflict-free.
// ---------------------------------------------------------------------------
__global__ __launch_bounds__(256) void k4_agg(
    const ushort* __restrict__ VpH,    // MEXT x D bf16 (rows >= NTOK are VQ)
    const float* __restrict__ S,       // MEXT x QN
    const int* __restrict__ indices,
    const void* __restrict__ pmask,
    const float* __restrict__ Wf, const float* __restrict__ bf,
    float* __restrict__ out)
{
    __shared__ int   idxs[PP];
    __shared__ int   mval[PP];
    __shared__ int   cidx[PP + 4];
    __shared__ int   cp[PP + 4];
    __shared__ float scT[PP + 2][QN];  // row0=self, 1..64=gathered, 65=zero pad
    __shared__ float red[QN][4];
    __shared__ float fwq[QN];
    __shared__ int   cntS;

    const int n = blockIdx.x;
    const int tid = threadIdx.x;

    // pos_mask storage-width detection (wave-uniform)
    const unsigned int* mw = (const unsigned int*)pmask;
    bool four = true;
#pragma unroll
    for (int i = 0; i < 16; ++i) {
        const unsigned int v = mw[i];
        four = four && (v == 0u || v == 1u || v == 0x3F800000u);
    }

    if (tid < PP) {
        idxs[tid] = indices[n * PP + tid];
        int mv;
        if (four) mv = (mw[n * PP + tid] != 0u);
        else      mv = (((const unsigned char*)pmask)[n * PP + tid] != 0);
        mval[tid] = mv;
        const bool a = (mv != 0);
        const unsigned long long m = __ballot(a);
        const int pos = __popcll(m & ((1ull << tid) - 1ull));
        if (a) { cidx[pos] = idxs[tid]; cp[pos] = tid; }
        if (tid == 0) cntS = (int)__popcll(m);
    }
    __syncthreads();

    // gather scores (p-major), full 1024-entry fill
    for (int e = tid; e < QN * PP; e += 256) {
        const int p = e >> 4, q = e & 15;
        scT[p + 1][q] = mval[p] ? S[idxs[p] * QN + q] : -INFINITY;
    }
    if (tid < QN) scT[0][tid] = S[(NTOK + tid) * QN + tid];   // s_self[q]
    __syncthreads();

    if (tid < 4) { cidx[cntS + tid] = 0; cp[cntS + tid] = PP; }  // pad entries
    if (tid < QN) {                                  // softmax over 65 per q
        const int q = tid;
        float m = -INFINITY;
        for (int j = 0; j <= PP; ++j) m = fmaxf(m, scT[j][q]);
        float s = 0.f;
        for (int j = 0; j <= PP; ++j) { const float e = __expf(scT[j][q] - m); scT[j][q] = e; s += e; }
        const float inv = 1.f / s;
        for (int j = 0; j <= PP; ++j) scT[j][q] *= inv;
        scT[PP + 1][q] = 0.f;                        // pad weight = 0
    }
    __syncthreads();

    const int cnt4 = (cntS + 3) & ~3;
    const int d0 = tid * 2;
    float pt[QN][2];
    {
        float2 vq[QN];
#pragma unroll
        for (int q = 0; q < QN; ++q)
            vq[q] = bfp2f2(*(const unsigned int*)&VpH[(size_t)(NTOK + q) * DD + d0]);
#pragma unroll
        for (int q = 0; q < QN; ++q) {
            const float w0 = scT[0][q];
            pt[q][0] = w0 * vq[q].x;
            pt[q][1] = w0 * vq[q].y;
        }
    }
    for (int j0 = 0; j0 < cnt4; j0 += 4) {
        float2 v[4]; int p[4];
#pragma unroll
        for (int pi = 0; pi < 4; ++pi) {
            v[pi] = bfp2f2(*(const unsigned int*)&VpH[(size_t)cidx[j0 + pi] * DD + d0]);
            p[pi] = cp[j0 + pi] + 1;
        }
#pragma unroll
        for (int pi = 0; pi < 4; ++pi) {
            const float4 wa = *(const float4*)&scT[p[pi]][0];
            const float4 wb = *(const float4*)&scT[p[pi]][4];
            const float4 wc = *(const float4*)&scT[p[pi]][8];
            const float4 wd = *(const float4*)&scT[p[pi]][12];
            const float vx = v[pi].x, vy = v[pi].y;
            pt[ 0][0] += wa.x*vx; pt[ 0][1] += wa.x*vy;
            pt[ 1][0] += wa.y*vx; pt[ 1][1] += wa.y*vy;
            pt[ 2][0] += wa.z*vx; pt[ 2][1] += wa.z*vy;
            pt[ 3][0] += wa.w*vx; pt[ 3][1] += wa.w*vy;
            pt[ 4][0] += wb.x*vx; pt[ 4][1] += wb.x*vy;
            pt[ 5][0] += wb.y*vx; pt[ 5][1] += wb.y*vy;
            pt[ 6][0] += wb.z*vx; pt[ 6][1] += wb.z*vy;
            pt[ 7][0] += wb.w*vx; pt[ 7][1] += wb.w*vy;
            pt[ 8][0] += wc.x*vx; pt[ 8][1] += wc.x*vy;
            pt[ 9][0] += wc.y*vx; pt[ 9][1] += wc.y*vy;
            pt[10][0] += wc.z*vx; pt[10][1] += wc.z*vy;
            pt[11][0] += wc.w*vx; pt[11][1] += wc.w*vy;
            pt[12][0] += wd.x*vx; pt[12][1] += wd.x*vy;
            pt[13][0] += wd.y*vx; pt[13][1] += wd.y*vy;
            pt[14][0] += wd.z*vx; pt[14][1] += wd.z*vy;
            pt[15][0] += wd.w*vx; pt[15][1] += wd.w*vy;
        }
    }

    // fusion logits f[q] = pt[q,:] . Wf + bf
    const float wf0 = Wf[d0], wf1 = Wf[d0 + 1];
    const int wid = tid >> 6, lane = tid & 63;
#pragma unroll
    for (int q = 0; q < QN; ++q) {
        float s = pt[q][0] * wf0 + pt[q][1] * wf1;
#pragma unroll
        for (int off = 32; off > 0; off >>= 1) s += __shfl_down(s, off, 64);
        if (lane == 0) red[q][wid] = s;
    }
    __syncthreads();
    if (tid == 0) {
        float f[QN];
        float m = -INFINITY;
#pragma unroll
        for (int q = 0; q < QN; ++q) {
            f[q] = red[q][0] + red[q][1] + red[q][2] + red[q][3] + bf[0];
            m = fmaxf(m, f[q]);
        }
        float ssum = 0.f;
#pragma unroll
        for (int q = 0; q < QN; ++q) { f[q] = __expf(f[q] - m); ssum += f[q]; }
        const float inv = 1.f / ssum;
#pragma unroll
        for (int q = 0; q < QN; ++q) fwq[q] = f[q] * inv;
    }
    __syncthreads();

    float o0 = 0.f, o1 = 0.f;
#pragma unroll
    for (int q = 0; q < QN; ++q) {
        const float w = fwq[q];
        o0 += pt[q][0] * w;
        o1 += pt[q][1] * w;
    }
    *(float2*)&out[(size_t)n * DD + d0] = make_float2(o0, o1);
}

// ---------------------------------------------------------------------------
extern "C" void kernel_launch(void* const* d_in, const int* in_sizes, int n_in,
                              void* d_out, int out_size, void* d_ws, size_t ws_size,
                              hipStream_t stream)
{
    const float* patch   = (const float*)d_in[0];
    const float* query   = (const float*)d_in[1];
    const float* Wk      = (const float*)d_in[2];
    const float* bk      = (const float*)d_in[3];
    const float* Wv      = (const float*)d_in[4];
    const float* bv      = (const float*)d_in[5];
    const float* Wf      = (const float*)d_in[6];
    const float* bf      = (const float*)d_in[7];
    const int*   indices = (const int*)d_in[8];
    const void*  pmask   = d_in[9];
    float* out = (float*)d_out;

    // ws: VpH bf16[MEXT*DD] | S f32[MEXT*QN] | c0 f32[16]
    //     | Xb bf16[MPAD*DD] | Bb bf16[NB*DD]     (~9.5 MB of 256 MiB ws)
    ushort* VpH = (ushort*)d_ws;
    float*  S   = (float*)(VpH + (size_t)MEXT * DD);
    float*  c0  = S + (size_t)MEXT * QN;
    ushort* Xb  = (ushort*)(c0 + 16);
    ushort* Bb  = Xb + (size_t)MPAD * DD;

    pack_all<<<dim3(1280), dim3(256), 0, stream>>>(patch, query, Wv, Wk, bk, Xb, Bb, c0);
    k2_mfma <<<dim3(10, 66), dim3(256), 0, stream>>>(Xb, Bb, bv, c0, VpH, S);
    k4_agg  <<<dim3(NGRP), dim3(256), 0, stream>>>(VpH, S, indices, pmask, Wf, bf, out);
}